// Round 2
// baseline (13417.462 us; speedup 1.0000x reference)
//
#include <hip/hip_runtime.h>
#include <hip/hip_cooperative_groups.h>
#include <math.h>

namespace cg = cooperative_groups;

#define T_ 64
#define B_ 32
#define V_ 32000
#define H_ 1024
#define EMB_ 512
#define EPS_ 1e-7f
#define COPY_ID_ 3

typedef __bf16 bf16x8 __attribute__((ext_vector_type(8)));
typedef float f32x4 __attribute__((ext_vector_type(4)));

__device__ __forceinline__ unsigned short f2bf(float x) {
    union { float f; unsigned int i; } v; v.f = x;
    unsigned int r = v.i + 0x7FFF + ((v.i >> 16) & 1);
    return (unsigned short)(r >> 16);
}
__device__ __forceinline__ float bf2f(unsigned short h) {
    union { unsigned int i; float f; } v; v.i = ((unsigned int)h) << 16;
    return v.f;
}
// split v into hi + lo bf16 (RNE); hi+lo reproduces v to ~2^-17 rel.
__device__ __forceinline__ void f2hilo(float v, unsigned short& h, unsigned short& l) {
    h = f2bf(v);
    l = f2bf(v - bf2f(h));
}

// ---------------------------------------------------------------------------
// One-time weight packing: gate-interleaved rows (i,f,g,o adjacent per unit),
// [Wih | Whh] concatenated along K, split into bf16 hi/lo.
// ---------------------------------------------------------------------------
__global__ __launch_bounds__(256) void pack_gates_kernel(
    const float* __restrict__ Wih, int Kih, const float* __restrict__ Whh,
    int Kout, unsigned short* __restrict__ hi, unsigned short* __restrict__ lo)
{
    int idx = blockIdx.x * 256 + threadIdx.x;   // float4 index, row-major [4096][Kout/4]
    int kq = Kout >> 2;
    int jp = idx / kq;
    if (jp >= 4096) return;
    int k = (idx - jp * kq) << 2;
    int j = (jp & 3) * H_ + (jp >> 2);
    float4 v = (k < Kih) ? *(const float4*)(Wih + (size_t)j * Kih + k)
                         : *(const float4*)(Whh + (size_t)j * H_ + (k - Kih));
    unsigned short h0,l0,h1,l1,h2,l2,h3,l3;
    f2hilo(v.x,h0,l0); f2hilo(v.y,h1,l1); f2hilo(v.z,h2,l2); f2hilo(v.w,h3,l3);
    ushort4 vh; vh.x=h0; vh.y=h1; vh.z=h2; vh.w=h3;
    ushort4 vl; vl.x=l0; vl.y=l1; vl.z=l2; vl.w=l3;
    ((ushort4*)hi)[idx] = vh;
    ((ushort4*)lo)[idx] = vl;
}

__global__ __launch_bounds__(256) void pack_plain_kernel(
    const float* __restrict__ W, unsigned short* __restrict__ hi,
    unsigned short* __restrict__ lo, int n4)
{
    int idx = blockIdx.x * 256 + threadIdx.x;
    if (idx >= n4) return;
    float4 v = ((const float4*)W)[idx];
    unsigned short h0,l0,h1,l1,h2,l2,h3,l3;
    f2hilo(v.x,h0,l0); f2hilo(v.y,h1,l1); f2hilo(v.z,h2,l2); f2hilo(v.w,h3,l3);
    ushort4 vh; vh.x=h0; vh.y=h1; vh.z=h2; vh.w=h3;
    ushort4 vl; vl.x=l0; vl.y=l1; vl.z=l2; vl.w=l3;
    ((ushort4*)hi)[idx] = vh;
    ((ushort4*)lo)[idx] = vl;
}

// Gather embeddings for all (t,b) up front into bf16 hi/lo: Xe[T*B][512].
__global__ __launch_bounds__(256) void embed_hilo_kernel(
    const float* __restrict__ E, const int* __restrict__ tok,
    unsigned short* __restrict__ Xh, unsigned short* __restrict__ Xl)
{
    int idx = blockIdx.x * 256 + threadIdx.x;   // over 2048*128 float4s
    int row = idx >> 7, k = (idx & 127) << 2;
    int tv = tok[row];
    float4 v = *(const float4*)(E + (size_t)tv * EMB_ + k);
    unsigned short h0,l0,h1,l1,h2,l2,h3,l3;
    f2hilo(v.x,h0,l0); f2hilo(v.y,h1,l1); f2hilo(v.z,h2,l2); f2hilo(v.w,h3,l3);
    ushort4 vh; vh.x=h0; vh.y=h1; vh.z=h2; vh.w=h3;
    ushort4 vl; vl.x=l0; vl.y=l1; vl.z=l2; vl.w=l3;
    ((ushort4*)Xh)[idx] = vh;
    ((ushort4*)Xl)[idx] = vl;
}

// Init ping-pong recurrent input buffers (parity 0): feed/h0cur zero,
// hprev slots from h0 initial states.
__global__ __launch_bounds__(256) void init_states_kernel(
    const float* __restrict__ h0i,
    unsigned short* __restrict__ x0h, unsigned short* __restrict__ x0l,
    unsigned short* __restrict__ x1h, unsigned short* __restrict__ x1l)
{
    int idx = blockIdx.x * 256 + threadIdx.x;   // 32*1024
    int b = idx >> 10, u = idx & 1023;
    unsigned short h, l;
    x0h[b*2048 + u] = 0; x0l[b*2048 + u] = 0;
    f2hilo(h0i[idx], h, l);
    x0h[b*2048 + 1024 + u] = h; x0l[b*2048 + 1024 + u] = l;
    x1h[b*2048 + u] = 0; x1l[b*2048 + u] = 0;
    f2hilo(h0i[32768 + idx], h, l);
    x1h[b*2048 + 1024 + u] = h; x1l[b*2048 + 1024 + u] = l;
}

// ---------------------------------------------------------------------------
// Persistent-loop phase bodies (device functions). 256 blocks x 512 threads.
// ---------------------------------------------------------------------------

// LSTM step via MFMA, split-bf16 3-term. Block owns 16 gate-interleaved rows
// (= 4 complete units), K split 8-way across waves, fused gate tail.
template<int K, int XE>
__device__ __forceinline__ void lstm_phase(
    const unsigned short* __restrict__ Xe_h, const unsigned short* __restrict__ Xe_l,
    const unsigned short* __restrict__ Xr_h, const unsigned short* __restrict__ Xr_l,
    const unsigned short* __restrict__ Wh,  const unsigned short* __restrict__ Wl,
    const float* __restrict__ bih, const float* __restrict__ bhh,
    float* __restrict__ c_io,
    unsigned short* d1h, unsigned short* d1l, int d1s, int d1o,
    unsigned short* d2h, unsigned short* d2l, int d2s, int d2o,
    float* hf32,
    float (*Gs)[32][16], float (*Gr)[16])
{
    const int tid = threadIdx.x;
    const int wave = tid >> 6, lane = tid & 63;
    const int quad = lane >> 4, l15 = lane & 15;
    const int n0 = blockIdx.x * 16;
    constexpr int Kq = K >> 3;           // per-wave K span (8 waves)
    const int kb = wave * Kq;
    const int col = quad * 8;
    f32x4 acc0 = {0.f,0.f,0.f,0.f}, acc1 = {0.f,0.f,0.f,0.f};
    const unsigned short* wrh = Wh + (size_t)(n0 + l15) * K + kb + col;
    const unsigned short* wrl = Wl + (size_t)(n0 + l15) * K + kb + col;
    #pragma unroll 4
    for (int ks = 0; ks < Kq; ks += 32) {
        const int k = kb + ks;
        const unsigned short *ah, *al; int as_;
        if (XE != 0 && k < XE) { ah = Xe_h + k + col; al = Xe_l + k + col; as_ = EMB_; }
        else                   { ah = Xr_h + (k - XE) + col; al = Xr_l + (k - XE) + col; as_ = 2048; }
        bf16x8 a0h = *(const bf16x8*)(ah + l15 * as_);
        bf16x8 a0l = *(const bf16x8*)(al + l15 * as_);
        bf16x8 a1h = *(const bf16x8*)(ah + (16 + l15) * as_);
        bf16x8 a1l = *(const bf16x8*)(al + (16 + l15) * as_);
        bf16x8 bh  = *(const bf16x8*)(wrh + ks);
        bf16x8 bl  = *(const bf16x8*)(wrl + ks);
        acc0 = __builtin_amdgcn_mfma_f32_16x16x32_bf16(a0h, bh, acc0, 0, 0, 0);
        acc1 = __builtin_amdgcn_mfma_f32_16x16x32_bf16(a1h, bh, acc1, 0, 0, 0);
        acc0 = __builtin_amdgcn_mfma_f32_16x16x32_bf16(a0h, bl, acc0, 0, 0, 0);
        acc1 = __builtin_amdgcn_mfma_f32_16x16x32_bf16(a1h, bl, acc1, 0, 0, 0);
        acc0 = __builtin_amdgcn_mfma_f32_16x16x32_bf16(a0l, bh, acc0, 0, 0, 0);
        acc1 = __builtin_amdgcn_mfma_f32_16x16x32_bf16(a1l, bh, acc1, 0, 0, 0);
    }
    // C/D layout: col = lane&15 (gate row), row = quad*4 + reg (batch) [m89]
    #pragma unroll
    for (int rr = 0; rr < 4; rr++) {
        Gs[wave][quad * 4 + rr][l15]      = acc0[rr];
        Gs[wave][16 + quad * 4 + rr][l15] = acc1[rr];
    }
    __syncthreads();
    {
        const int b = tid >> 4, nl = tid & 15;   // 512 outputs, 1 pass
        float g = 0.f;
        #pragma unroll
        for (int w = 0; w < 8; w++) g += Gs[w][b][nl];
        const int jn = n0 + nl;
        const int j = (jn & 3) * H_ + (jn >> 2); // original (un-interleaved) row
        Gr[b][nl] = g + bih[j] + bhh[j];
    }
    __syncthreads();
    if (tid < 128) {
        const int b = tid & 31, ul = tid >> 5;
        const int u = (n0 >> 2) + ul;
        const float gi = Gr[b][ul * 4 + 0];
        const float gf = Gr[b][ul * 4 + 1];
        const float gg = Gr[b][ul * 4 + 2];
        const float go = Gr[b][ul * 4 + 3];
        const float cold = c_io[b * H_ + u];
        const float si = 1.f / (1.f + __expf(-gi));
        const float sf = 1.f / (1.f + __expf(-gf));
        const float so = 1.f / (1.f + __expf(-go));
        const float cn = sf * cold + si * tanhf(gg);
        const float hn = so * tanhf(cn);
        c_io[b * H_ + u] = cn;
        unsigned short hh, hl;
        f2hilo(hn, hh, hl);
        d1h[b * d1s + d1o + u] = hh;
        d1l[b * d1s + d1o + u] = hl;
        d2h[b * d2s + d2o + u] = hh;
        d2l[b * d2s + d2o + u] = hl;
        if (hf32) hf32[b * H_ + u] = hn;
    }
}

// Small GEMM out[32,1024] = X[32,K] @ W[1024,K]^T + bias, K split 8-way.
// MODE 0: fp32 out (keybuf) + atomic partial of score(s=t) = keyv . htop.
// MODE 1: bf16 out (combbf) + hi/lo feed slot.
template<int K, int MODE>
__device__ __forceinline__ void gemm32_phase(
    const unsigned short* __restrict__ Xh, const unsigned short* __restrict__ Xl,
    const unsigned short* __restrict__ Wh, const unsigned short* __restrict__ Wl,
    const float* __restrict__ bias,
    float* outf, unsigned short* outbf,
    unsigned short* dh, unsigned short* dl,
    const float* htop, float* score_row,
    float (*Gs)[32][16])
{
    const int tid = threadIdx.x;
    const int wave = tid >> 6, lane = tid & 63;
    const int quad = lane >> 4, l15 = lane & 15;
    const int n0 = blockIdx.x * 16;
    constexpr int Kq = K >> 3;
    const int kb = wave * Kq;
    const int col = quad * 8;
    f32x4 acc0 = {0.f,0.f,0.f,0.f}, acc1 = {0.f,0.f,0.f,0.f};
    const unsigned short* x0h = Xh + (size_t)l15 * K + kb + col;
    const unsigned short* x0l = Xl + (size_t)l15 * K + kb + col;
    const unsigned short* x1h = Xh + (size_t)(16 + l15) * K + kb + col;
    const unsigned short* x1l = Xl + (size_t)(16 + l15) * K + kb + col;
    const unsigned short* wrh = Wh + (size_t)(n0 + l15) * K + kb + col;
    const unsigned short* wrl = Wl + (size_t)(n0 + l15) * K + kb + col;
    #pragma unroll 4
    for (int ks = 0; ks < Kq; ks += 32) {
        bf16x8 a0h = *(const bf16x8*)(x0h + ks);
        bf16x8 a0l = *(const bf16x8*)(x0l + ks);
        bf16x8 a1h = *(const bf16x8*)(x1h + ks);
        bf16x8 a1l = *(const bf16x8*)(x1l + ks);
        bf16x8 bh  = *(const bf16x8*)(wrh + ks);
        bf16x8 bl  = *(const bf16x8*)(wrl + ks);
        acc0 = __builtin_amdgcn_mfma_f32_16x16x32_bf16(a0h, bh, acc0, 0, 0, 0);
        acc1 = __builtin_amdgcn_mfma_f32_16x16x32_bf16(a1h, bh, acc1, 0, 0, 0);
        acc0 = __builtin_amdgcn_mfma_f32_16x16x32_bf16(a0h, bl, acc0, 0, 0, 0);
        acc1 = __builtin_amdgcn_mfma_f32_16x16x32_bf16(a1h, bl, acc1, 0, 0, 0);
        acc0 = __builtin_amdgcn_mfma_f32_16x16x32_bf16(a0l, bh, acc0, 0, 0, 0);
        acc1 = __builtin_amdgcn_mfma_f32_16x16x32_bf16(a1l, bh, acc1, 0, 0, 0);
    }
    #pragma unroll
    for (int rr = 0; rr < 4; rr++) {
        Gs[wave][quad * 4 + rr][l15]      = acc0[rr];
        Gs[wave][16 + quad * 4 + rr][l15] = acc1[rr];
    }
    __syncthreads();
    {
        const int b = tid >> 4, nl = tid & 15;
        const int n = n0 + nl;
        float v = bias[n];
        #pragma unroll
        for (int w = 0; w < 8; w++) v += Gs[w][b][nl];
        if (MODE == 0) {
            outf[b * H_ + n] = v;
            float pv = v * htop[b * H_ + n];
            #pragma unroll
            for (int off = 8; off > 0; off >>= 1) pv += __shfl_down(pv, off, 16);
            if ((tid & 15) == 0) atomicAdd(score_row + b, pv);
        } else {
            outbf[b * H_ + n] = f2bf(v);
            unsigned short hh, hl;
            f2hilo(v, hh, hl);
            dh[b * 2048 + n] = hh;
            dl[b * 2048 + n] = hl;
        }
    }
}

// Historical scores s < t: one (s,b) dot per wave-iteration across blocks 64..255.
__device__ __forceinline__ void scores_phase(
    int t, const float* __restrict__ hbuf, const float* __restrict__ keybuf,
    float* __restrict__ score_g)
{
    const int gw = (blockIdx.x - 64) * 8 + (threadIdx.x >> 6);
    const int lane = threadIdx.x & 63;
    const float* ht_t = hbuf + (size_t)t * B_ * H_;
    for (int p = gw; p < t * 32; p += 192 * 8) {
        const int s = p >> 5, b = p & 31;
        const float* kv = keybuf + ((size_t)s * B_ + b) * H_;
        const float* ht = ht_t + (size_t)b * H_;
        float acc = 0.f;
        #pragma unroll
        for (int j = 0; j < 16; j++) acc += kv[lane + 64 * j] * ht[lane + 64 * j];
        #pragma unroll
        for (int off = 32; off > 0; off >>= 1) acc += __shfl_down(acc, off, 64);
        if (lane == 0) score_g[s * 32 + b] = acc;
    }
}

// Softmax + summary. 8 blocks per batch row (slice of 128 H-cols each);
// softmax recomputed redundantly per block (64 values, cheap & deterministic).
__device__ __forceinline__ void attn_phase(
    int t, const int* __restrict__ tok, const float* __restrict__ hbuf,
    const float* __restrict__ score_g, float* __restrict__ dist,
    unsigned short* __restrict__ cath, unsigned short* __restrict__ catl,
    float* dsh, float (*smp)[128])
{
    const int b = blockIdx.x >> 3, slice = blockIdx.x & 7;
    const int tid = threadIdx.x;
    if (tid < 64) {
        float v = (tid <= t) ? score_g[tid * 32 + b] +
                  ((tok[tid * 32 + b] == 0) ? -99999.0f : 0.0f) : -1e30f;
        float m = v;
        #pragma unroll
        for (int off = 32; off > 0; off >>= 1) m = fmaxf(m, __shfl_down(m, off, 64));
        m = __shfl(m, 0, 64);
        float e = (tid <= t) ? __expf(v - m) : 0.f;
        float ss = e;
        #pragma unroll
        for (int off = 32; off > 0; off >>= 1) ss += __shfl_down(ss, off, 64);
        ss = __shfl(ss, 0, 64);
        dsh[tid] = e / ss;
    }
    __syncthreads();
    const int c = tid & 127, q = tid >> 7;
    const int col = slice * 128 + c;
    float sm = 0.f;
    for (int s = q; s <= t; s += 4)
        sm += dsh[s] * hbuf[((size_t)s * B_ + b) * H_ + col];
    smp[q][c] = sm;
    __syncthreads();
    if (tid < 128) {
        const int c2 = slice * 128 + tid;
        float total = smp[0][tid] + smp[1][tid] + smp[2][tid] + smp[3][tid];
        unsigned short hh, hl;
        f2hilo(total, hh, hl);
        cath[b * 2048 + 1024 + c2] = hh;
        catl[b * 2048 + 1024 + c2] = hl;
        const float htv = hbuf[((size_t)t * B_ + b) * H_ + c2];
        f2hilo(htv, hh, hl);
        cath[b * 2048 + c2] = hh;
        catl[b * 2048 + c2] = hl;
    }
    if (slice == 0 && tid <= t)
        dist[((size_t)t * T_ + tid) * B_ + b] = dsh[tid];
}

// ---------------------------------------------------------------------------
// Persistent cooperative kernel: the whole 64-step recurrence, 5 grid syncs
// per step instead of 5 kernel launches.
// ---------------------------------------------------------------------------
struct DecParams {
    const int* tok;
    const unsigned short *Xeh, *Xel;
    unsigned short *xr0h, *xr0l, *xr1h, *xr1l;
    const unsigned short *W0h, *W0l, *W1h, *W1l, *Wkh, *Wkl, *Wch, *Wcl;
    const float *bih0, *bhh0, *bih1, *bhh1, *bk, *bc;
    float *c0b, *c1b;
    float *hbuf, *keybuf, *score_g, *dist;
    unsigned short *hbh, *hbl, *cath, *catl, *combbf;
};

__global__ __launch_bounds__(512) void decode_loop_kernel(DecParams p)
{
    cg::grid_group gg = cg::this_grid();
    __shared__ __align__(16) float Gs[8][32][16];
    __shared__ float Gr[32][16];
    __shared__ float dsh[64];
    __shared__ float smp[4][128];
    const int blk = blockIdx.x;
    const int tid = threadIdx.x;
    for (int t = 0; t < T_; t++) {
        const size_t cur = (size_t)(t & 1) * B_ * 2048;
        const size_t nxt = (size_t)((t + 1) & 1) * B_ * 2048;
        const size_t to1 = (size_t)t * B_ * H_;
        // zero the s=t score row (consumed by P3 atomics, 2 syncs later)
        if (blk == 0 && tid < 32) p.score_g[t * 32 + tid] = 0.f;
        // P1: layer 0.  X = [Xe(t) | feed | h0prev]
        lstm_phase<2560, 512>(
            p.Xeh + (size_t)t * B_ * EMB_, p.Xel + (size_t)t * B_ * EMB_,
            p.xr0h + cur, p.xr0l + cur, p.W0h, p.W0l, p.bih0, p.bhh0, p.c0b,
            p.xr0h + nxt, p.xr0l + nxt, 2048, 1024,
            p.xr1h + cur, p.xr1l + cur, 2048, 0,
            nullptr, Gs, Gr);
        gg.sync();
        // P2: layer 1.  X = [h0cur | h1prev]
        lstm_phase<2048, 0>(
            p.xr1h + cur, p.xr1l + cur, p.xr1h + cur, p.xr1l + cur,
            p.W1h, p.W1l, p.bih1, p.bhh1, p.c1b,
            p.xr1h + nxt, p.xr1l + nxt, 2048, 1024,
            p.hbh + to1, p.hbl + to1, 1024, 0,
            p.hbuf + to1, Gs, Gr);
        gg.sync();
        // P3: keyv(t) + score(t) partials (blocks 0..63) || scores s<t (64..255)
        if (blk < 64)
            gemm32_phase<1024, 0>(p.hbh + to1, p.hbl + to1, p.Wkh, p.Wkl, p.bk,
                p.keybuf + to1, nullptr, nullptr, nullptr,
                p.hbuf + to1, p.score_g + t * 32, Gs);
        else
            scores_phase(t, p.hbuf, p.keybuf, p.score_g);
        gg.sync();
        // P4: softmax + summary + cat + dist
        attn_phase(t, p.tok, p.hbuf, p.score_g, p.dist, p.cath, p.catl, dsh, smp);
        gg.sync();
        // P5: comb = cat @ Wc^T + bc -> combbf + next feed slot (blocks 0..63)
        if (blk < 64)
            gemm32_phase<2048, 1>(p.cath, p.catl, p.Wch, p.Wcl, p.bc,
                nullptr, p.combbf + to1, p.xr0h + nxt, p.xr0l + nxt,
                nullptr, nullptr, Gs);
        gg.sync();
    }
}

// ---------------------------------------------------------------------------
// fp32 -> bf16 cast (n4 float4 groups) — used for Wp only.
// ---------------------------------------------------------------------------
__global__ __launch_bounds__(256) void cast_bf16_kernel(
    const float* __restrict__ src, unsigned short* __restrict__ dst, int n4)
{
    int idx = blockIdx.x * 256 + threadIdx.x;
    int stride = gridDim.x * 256;
    for (int i = idx; i < n4; i += stride) {
        float4 v = ((const float4*)src)[i];
        ushort4 o;
        o.x = f2bf(v.x); o.y = f2bf(v.y); o.z = f2bf(v.z); o.w = f2bf(v.w);
        ((ushort4*)dst)[i] = o;
    }
}

// ---------------------------------------------------------------------------
// Logits GEMM: (2048 x 1024) @ Wp^T (32000 x 1024) + bp, bf16 MFMA 16x16x32.
// ---------------------------------------------------------------------------
__global__ __launch_bounds__(256) void logits_mfma_kernel(
    const __bf16* __restrict__ Abf, const __bf16* __restrict__ Bbf,
    const float* __restrict__ bp, float* __restrict__ out)
{
    __shared__ __align__(16) __bf16 As[128 * 32];
    __shared__ __align__(16) __bf16 Bs[128 * 32];
    const int tid = threadIdx.x;
    const int lane = tid & 63;
    const int wave = tid >> 6;
    const int quad = lane >> 4, l15 = lane & 15;
    const int m0 = blockIdx.y * 128, n0 = blockIdx.x * 128;
    const int wm = wave >> 1, wn = wave & 1;
    const f32x4 vzero = {0.f, 0.f, 0.f, 0.f};
    f32x4 acc[4][4];
    #pragma unroll
    for (int mt = 0; mt < 4; mt++)
        #pragma unroll
        for (int nt = 0; nt < 4; nt++) acc[mt][nt] = vzero;

    for (int k0 = 0; k0 < 1024; k0 += 32) {
        #pragma unroll
        for (int i = 0; i < 2; i++) {
            int idx = i * 256 + tid;
            int row = idx >> 2, co = (idx & 3) * 8;
            ((uint4*)As)[idx] = *(const uint4*)(Abf + (size_t)(m0 + row) * 1024 + k0 + co);
            ((uint4*)Bs)[idx] = *(const uint4*)(Bbf + (size_t)(n0 + row) * 1024 + k0 + co);
        }
        __syncthreads();
        bf16x8 af[4], bfr[4];
        #pragma unroll
        for (int mt = 0; mt < 4; mt++)
            af[mt] = *(const bf16x8*)&As[(wm * 64 + mt * 16 + l15) * 32 + quad * 8];
        #pragma unroll
        for (int nt = 0; nt < 4; nt++)
            bfr[nt] = *(const bf16x8*)&Bs[(wn * 64 + nt * 16 + l15) * 32 + quad * 8];
        #pragma unroll
        for (int mt = 0; mt < 4; mt++)
            #pragma unroll
            for (int nt = 0; nt < 4; nt++)
                acc[mt][nt] = __builtin_amdgcn_mfma_f32_16x16x32_bf16(
                    af[mt], bfr[nt], acc[mt][nt], 0, 0, 0);
        __syncthreads();
    }
    #pragma unroll
    for (int mt = 0; mt < 4; mt++) {
        #pragma unroll
        for (int nt = 0; nt < 4; nt++) {
            int gcol = n0 + wn * 64 + nt * 16 + l15;
            int growb = m0 + wm * 64 + mt * 16 + quad * 4;
            float bpv = bp[gcol];
            #pragma unroll
            for (int rr = 0; rr < 4; rr++)
                out[(size_t)(growb + rr) * V_ + gcol] = acc[mt][nt][rr] + bpv;
        }
    }
}

// ---------------------------------------------------------------------------
// Per-row max / sumexp / copy-weight from fp32 logits. Grid: T*B blocks.
// ---------------------------------------------------------------------------
__global__ __launch_bounds__(256) void rowstats_kernel(
    const float* __restrict__ logits, float* __restrict__ stats)
{
    const int row = blockIdx.x; const int tid = threadIdx.x;
    const float4* p4 = (const float4*)(logits + (size_t)row * V_);
    __shared__ float red[8];
    const int lane = tid & 63, wave = tid >> 6;
    float m = -1e30f;
    for (int i = tid; i < V_ / 4; i += 256) {
        float4 u = p4[i];
        m = fmaxf(m, fmaxf(fmaxf(u.x, u.y), fmaxf(u.z, u.w)));
    }
    #pragma unroll
    for (int off = 32; off > 0; off >>= 1) m = fmaxf(m, __shfl_down(m, off, 64));
    if (lane == 0) red[wave] = m;
    __syncthreads();
    if (tid == 0) {
        float mm = red[0];
        for (int w = 1; w < 4; w++) mm = fmaxf(mm, red[w]);
        red[4] = mm;
    }
    __syncthreads();
    const float M = red[4];
    float s = 0.f;
    for (int i = tid; i < V_ / 4; i += 256) {
        float4 u = p4[i];
        s += __expf(u.x - M) + __expf(u.y - M) + __expf(u.z - M) + __expf(u.w - M);
    }
    #pragma unroll
    for (int off = 32; off > 0; off >>= 1) s += __shfl_down(s, off, 64);
    if (lane == 0) red[wave] = s;
    __syncthreads();
    if (tid == 0) {
        float S = red[0] + red[1] + red[2] + red[3];
        float lc = logits[(size_t)row * V_ + COPY_ID_];
        float cw = __expf(lc - M) / S;
        stats[row * 4 + 0] = M;
        stats[row * 4 + 1] = S;
        stats[row * 4 + 2] = cw;
    }
}

__global__ __launch_bounds__(64) void fixup_compute_kernel(
    const float* __restrict__ logits, const float* __restrict__ stats,
    const int* __restrict__ tokens, const float* __restrict__ dist_all,
    float* __restrict__ fixval)
{
    const int bid = blockIdx.x;          // t*B + b
    const int t = bid >> 5, b = bid & 31;
    const int s = threadIdx.x;
    if (s > t) return;
    const int v = tokens[s * B_ + b];
    float d = 0.f;
    for (int s2 = 0; s2 <= t; s2++)
        if (tokens[s2 * B_ + b] == v)
            d += dist_all[((size_t)t * T_ + s2) * B_ + b];
    const float M = stats[bid * 4], S = stats[bid * 4 + 1], cw = stats[bid * 4 + 2];
    const float l = logits[(size_t)bid * V_ + v];
    const float p = __expf(l - M) / S;
    fixval[((size_t)t * T_ + s) * B_ + b] = __logf(cw * (EPS_ + d) + (1.f - cw) * p);
}

__global__ __launch_bounds__(256) void finalize_kernel(
    float* __restrict__ logits, const float* __restrict__ stats)
{
    const int row = blockIdx.x; const int tid = threadIdx.x;
    float4* p4 = (float4*)(logits + (size_t)row * V_);
    const float M = stats[row * 4], S = stats[row * 4 + 1], cw = stats[row * 4 + 2];
    const float inv = 1.f / S, omc = 1.f - cw, ce = cw * EPS_;
    for (int i = tid; i < V_ / 4; i += 256) {
        float4 u = p4[i];
        u.x = __logf(omc * (__expf(u.x - M) * inv) + ce);
        u.y = __logf(omc * (__expf(u.y - M) * inv) + ce);
        u.z = __logf(omc * (__expf(u.z - M) * inv) + ce);
        u.w = __logf(omc * (__expf(u.w - M) * inv) + ce);
        p4[i] = u;
    }
}

__global__ __launch_bounds__(64) void fixup_apply_kernel(
    float* __restrict__ logits, const int* __restrict__ tokens,
    const float* __restrict__ fixval)
{
    const int bid = blockIdx.x; const int t = bid >> 5, b = bid & 31;
    const int s = threadIdx.x;
    if (s > t) return;
    const int v = tokens[s * B_ + b];
    logits[(size_t)bid * V_ + v] = fixval[((size_t)t * T_ + s) * B_ + b];
}

// ---------------------------------------------------------------------------
extern "C" void kernel_launch(void* const* d_in, const int* in_sizes, int n_in,
                              void* d_out, int out_size, void* d_ws, size_t ws_size,
                              hipStream_t stream)
{
    const int*   tok  = (const int*)d_in[0];
    const float* h0i  = (const float*)d_in[1];
    const float* c0i  = (const float*)d_in[2];
    const float* E    = (const float*)d_in[3];
    const float* Wih0 = (const float*)d_in[4];
    const float* Whh0 = (const float*)d_in[5];
    const float* bih0 = (const float*)d_in[6];
    const float* bhh0 = (const float*)d_in[7];
    const float* Wih1 = (const float*)d_in[8];
    const float* Whh1 = (const float*)d_in[9];
    const float* bih1 = (const float*)d_in[10];
    const float* bhh1 = (const float*)d_in[11];
    const float* Wk   = (const float*)d_in[12];
    const float* bk   = (const float*)d_in[13];
    const float* Wc   = (const float*)d_in[14];
    const float* bc   = (const float*)d_in[15];
    const float* Wp   = (const float*)d_in[16];
    const float* bp   = (const float*)d_in[17];
    float* out = (float*)d_out;

    // ---- workspace (fp32 side) ----
    float* ws = (float*)d_ws;
    size_t off = 0;
    float* hbuf   = ws + off; off += (size_t)T_ * B_ * H_;     // fp32 htop, attn input
    float* keybuf = ws + off; off += (size_t)T_ * B_ * H_;
    float* dist   = ws + off; off += (size_t)T_ * T_ * B_;
    float* fixv   = ws + off; off += (size_t)T_ * T_ * B_;
    float* c0b    = ws + off; off += B_ * H_;
    float* c1b    = ws + off; off += B_ * H_;
    float* stats  = ws + off; off += (size_t)T_ * B_ * 4;
    float* score_g= ws + off; off += (size_t)T_ * B_;
    unsigned short* combbf = (unsigned short*)(ws + off); off += (size_t)T_ * B_ * H_ / 2;
    unsigned short* Wpbf   = (unsigned short*)(ws + off); off += (size_t)V_ * H_ / 2;

    // ---- scratch carved from d_out (262 MB; only the epilogue writes logits,
    //      all of this is dead by then). ~102 MB total. ----
    unsigned short* os = (unsigned short*)d_out;
    size_t so = 0;
    unsigned short* W0h = os + so; so += (size_t)4096 * 2560;
    unsigned short* W0l = os + so; so += (size_t)4096 * 2560;
    unsigned short* W1h = os + so; so += (size_t)4096 * 2048;
    unsigned short* W1l = os + so; so += (size_t)4096 * 2048;
    unsigned short* Wkh = os + so; so += (size_t)1024 * 1024;
    unsigned short* Wkl = os + so; so += (size_t)1024 * 1024;
    unsigned short* Wch = os + so; so += (size_t)1024 * 2048;
    unsigned short* Wcl = os + so; so += (size_t)1024 * 2048;
    unsigned short* Xeh = os + so; so += (size_t)T_ * B_ * EMB_;
    unsigned short* Xel = os + so; so += (size_t)T_ * B_ * EMB_;
    unsigned short* xr0h = os + so; so += (size_t)2 * B_ * 2048;  // [2][32][feed|h0prev]
    unsigned short* xr0l = os + so; so += (size_t)2 * B_ * 2048;
    unsigned short* xr1h = os + so; so += (size_t)2 * B_ * 2048;  // [2][32][h0cur|h1prev]
    unsigned short* xr1l = os + so; so += (size_t)2 * B_ * 2048;
    unsigned short* hbh  = os + so; so += (size_t)T_ * B_ * H_;   // htop hi (keyv input)
    unsigned short* hbl  = os + so; so += (size_t)T_ * B_ * H_;
    unsigned short* cath = os + so; so += (size_t)B_ * 2048;
    unsigned short* catl = os + so; so += (size_t)B_ * 2048;

    // ---- one-time prep ----
    hipMemcpyAsync(c0b, c0i,           B_ * H_ * 4, hipMemcpyDeviceToDevice, stream);
    hipMemcpyAsync(c1b, c0i + B_ * H_, B_ * H_ * 4, hipMemcpyDeviceToDevice, stream);
    pack_gates_kernel<<<10240, 256, 0, stream>>>(Wih0, 1536, Whh0, 2560, W0h, W0l);
    pack_gates_kernel<<<8192,  256, 0, stream>>>(Wih1, 1024, Whh1, 2048, W1h, W1l);
    pack_plain_kernel<<<1024,  256, 0, stream>>>(Wk, Wkh, Wkl, 1024 * 1024 / 4);
    pack_plain_kernel<<<2048,  256, 0, stream>>>(Wc, Wch, Wcl, 1024 * 2048 / 4);
    embed_hilo_kernel<<<1024,  256, 0, stream>>>(E, tok, Xeh, Xel);
    init_states_kernel<<<128,  256, 0, stream>>>(h0i, xr0h, xr0l, xr1h, xr1l);
    cast_bf16_kernel<<<2048,   256, 0, stream>>>(Wp, Wpbf, V_ * H_ / 4);

    // ---- recurrent loop: one persistent cooperative kernel ----
    DecParams P;
    P.tok = tok; P.Xeh = Xeh; P.Xel = Xel;
    P.xr0h = xr0h; P.xr0l = xr0l; P.xr1h = xr1h; P.xr1l = xr1l;
    P.W0h = W0h; P.W0l = W0l; P.W1h = W1h; P.W1l = W1l;
    P.Wkh = Wkh; P.Wkl = Wkl; P.Wch = Wch; P.Wcl = Wcl;
    P.bih0 = bih0; P.bhh0 = bhh0; P.bih1 = bih1; P.bhh1 = bhh1;
    P.bk = bk; P.bc = bc;
    P.c0b = c0b; P.c1b = c1b;
    P.hbuf = hbuf; P.keybuf = keybuf; P.score_g = score_g; P.dist = dist;
    P.hbh = hbh; P.hbl = hbl; P.cath = cath; P.catl = catl; P.combbf = combbf;
    void* kargs[] = { (void*)&P };
    hipLaunchCooperativeKernel(reinterpret_cast<void*>(decode_loop_kernel),
                               dim3(256), dim3(512), kargs, 0, stream);

    // ---- epilogue (overwrites the d_out scratch with real logits) ----
    dim3 g1(V_ / 128, (T_ * B_) / 128);
    logits_mfma_kernel<<<g1, 256, 0, stream>>>(
        (const __bf16*)combbf, (const __bf16*)Wpbf, bp, out);
    rowstats_kernel<<<T_ * B_, 256, 0, stream>>>(out, stats);
    fixup_compute_kernel<<<T_ * B_, T_, 0, stream>>>(out, stats, tok, dist, fixv);
    finalize_kernel<<<T_ * B_, 256, 0, stream>>>(out, stats);
    fixup_apply_kernel<<<T_ * B_, T_, 0, stream>>>(out, tok, fixv);
}

// Round 4
// 7711.968 us; speedup vs baseline: 1.7398x; 1.7398x over previous
//
#include <hip/hip_runtime.h>
#include <math.h>

#define T_ 64
#define B_ 32
#define V_ 32000
#define H_ 1024
#define EMB_ 512
#define EPS_ 1e-7f
#define COPY_ID_ 3

typedef __bf16 bf16x8 __attribute__((ext_vector_type(8)));
typedef float f32x4 __attribute__((ext_vector_type(4)));

__device__ __forceinline__ unsigned short f2bf(float x) {
    union { float f; unsigned int i; } v; v.f = x;
    unsigned int r = v.i + 0x7FFF + ((v.i >> 16) & 1);
    return (unsigned short)(r >> 16);
}
__device__ __forceinline__ float bf2f(unsigned short h) {
    union { unsigned int i; float f; } v; v.i = ((unsigned int)h) << 16;
    return v.f;
}
// split v into hi + lo bf16 (RNE); hi+lo reproduces v to ~2^-17 rel.
__device__ __forceinline__ void f2hilo(float v, unsigned short& h, unsigned short& l) {
    h = f2bf(v);
    l = f2bf(v - bf2f(h));
}

// ---------------------------------------------------------------------------
// Fast grid barrier: two-level (16 groups x 16 blocks), monotonic counters
// (no reset races), agent-scope atomics. Release chain: arrival ACQ_REL ->
// group-closer ACQ_REL on root -> gen ACQ_REL; spinners exit via ACQUIRE load.
// Spin is RELAXED + s_sleep; a ~0.2s realtime timeout converts any deadlock
// into a (loud) wrong answer instead of a GPU hang. Counters on separate
// 128B cache lines. Requires all blocks resident (cooperative launch).
// ---------------------------------------------------------------------------
__device__ __forceinline__ void gbar_sync(unsigned int* grp, unsigned int* root,
                                          unsigned int* gen, unsigned int epoch)
{
    __syncthreads();
    if (threadIdx.x == 0) {
        const int g = blockIdx.x >> 4;      // 16 groups of 16 blocks
        unsigned int v = __hip_atomic_fetch_add(&grp[g * 32], 1u,
                             __ATOMIC_ACQ_REL, __HIP_MEMORY_SCOPE_AGENT);
        if ((v & 15u) == 15u) {
            unsigned int r = __hip_atomic_fetch_add(root, 1u,
                                 __ATOMIC_ACQ_REL, __HIP_MEMORY_SCOPE_AGENT);
            if ((r & 15u) == 15u) {
                __hip_atomic_fetch_add(gen, 1u,
                    __ATOMIC_ACQ_REL, __HIP_MEMORY_SCOPE_AGENT);
            }
        }
        unsigned long long t0 = __builtin_amdgcn_s_memrealtime(); // 100 MHz
        while (__hip_atomic_load(gen, __ATOMIC_RELAXED,
                                 __HIP_MEMORY_SCOPE_AGENT) < epoch) {
            __builtin_amdgcn_s_sleep(4);
            if (__builtin_amdgcn_s_memrealtime() - t0 > 20000000ull) break;
        }
        (void)__hip_atomic_load(gen, __ATOMIC_ACQUIRE, __HIP_MEMORY_SCOPE_AGENT);
    }
    __syncthreads();
}

// ---------------------------------------------------------------------------
// One-time weight packing: gate-interleaved rows (i,f,g,o adjacent per unit),
// [Wih | Whh] concatenated along K, split into bf16 hi/lo.
// ---------------------------------------------------------------------------
__global__ __launch_bounds__(256) void pack_gates_kernel(
    const float* __restrict__ Wih, int Kih, const float* __restrict__ Whh,
    int Kout, unsigned short* __restrict__ hi, unsigned short* __restrict__ lo)
{
    int idx = blockIdx.x * 256 + threadIdx.x;   // float4 index, row-major [4096][Kout/4]
    int kq = Kout >> 2;
    int jp = idx / kq;
    if (jp >= 4096) return;
    int k = (idx - jp * kq) << 2;
    int j = (jp & 3) * H_ + (jp >> 2);
    float4 v = (k < Kih) ? *(const float4*)(Wih + (size_t)j * Kih + k)
                         : *(const float4*)(Whh + (size_t)j * H_ + (k - Kih));
    unsigned short h0,l0,h1,l1,h2,l2,h3,l3;
    f2hilo(v.x,h0,l0); f2hilo(v.y,h1,l1); f2hilo(v.z,h2,l2); f2hilo(v.w,h3,l3);
    ushort4 vh; vh.x=h0; vh.y=h1; vh.z=h2; vh.w=h3;
    ushort4 vl; vl.x=l0; vl.y=l1; vl.z=l2; vl.w=l3;
    ((ushort4*)hi)[idx] = vh;
    ((ushort4*)lo)[idx] = vl;
}

__global__ __launch_bounds__(256) void pack_plain_kernel(
    const float* __restrict__ W, unsigned short* __restrict__ hi,
    unsigned short* __restrict__ lo, int n4)
{
    int idx = blockIdx.x * 256 + threadIdx.x;
    if (idx >= n4) return;
    float4 v = ((const float4*)W)[idx];
    unsigned short h0,l0,h1,l1,h2,l2,h3,l3;
    f2hilo(v.x,h0,l0); f2hilo(v.y,h1,l1); f2hilo(v.z,h2,l2); f2hilo(v.w,h3,l3);
    ushort4 vh; vh.x=h0; vh.y=h1; vh.z=h2; vh.w=h3;
    ushort4 vl; vl.x=l0; vl.y=l1; vl.z=l2; vl.w=l3;
    ((ushort4*)hi)[idx] = vh;
    ((ushort4*)lo)[idx] = vl;
}

// Gather embeddings for all (t,b) up front into bf16 hi/lo: Xe[T*B][512].
__global__ __launch_bounds__(256) void embed_hilo_kernel(
    const float* __restrict__ E, const int* __restrict__ tok,
    unsigned short* __restrict__ Xh, unsigned short* __restrict__ Xl)
{
    int idx = blockIdx.x * 256 + threadIdx.x;   // over 2048*128 float4s
    int row = idx >> 7, k = (idx & 127) << 2;
    int tv = tok[row];
    float4 v = *(const float4*)(E + (size_t)tv * EMB_ + k);
    unsigned short h0,l0,h1,l1,h2,l2,h3,l3;
    f2hilo(v.x,h0,l0); f2hilo(v.y,h1,l1); f2hilo(v.z,h2,l2); f2hilo(v.w,h3,l3);
    ushort4 vh; vh.x=h0; vh.y=h1; vh.z=h2; vh.w=h3;
    ushort4 vl; vl.x=l0; vl.y=l1; vl.z=l2; vl.w=l3;
    ((ushort4*)Xh)[idx] = vh;
    ((ushort4*)Xl)[idx] = vl;
}

// Init ping-pong recurrent input buffers (parity 0): feed/h0cur zero,
// hprev slots from h0 initial states.
__global__ __launch_bounds__(256) void init_states_kernel(
    const float* __restrict__ h0i,
    unsigned short* __restrict__ x0h, unsigned short* __restrict__ x0l,
    unsigned short* __restrict__ x1h, unsigned short* __restrict__ x1l)
{
    int idx = blockIdx.x * 256 + threadIdx.x;   // 32*1024
    int b = idx >> 10, u = idx & 1023;
    unsigned short h, l;
    x0h[b*2048 + u] = 0; x0l[b*2048 + u] = 0;
    f2hilo(h0i[idx], h, l);
    x0h[b*2048 + 1024 + u] = h; x0l[b*2048 + 1024 + u] = l;
    x1h[b*2048 + u] = 0; x1l[b*2048 + u] = 0;
    f2hilo(h0i[32768 + idx], h, l);
    x1h[b*2048 + 1024 + u] = h; x1l[b*2048 + 1024 + u] = l;
}

// ---------------------------------------------------------------------------
// Persistent-loop phase bodies (device functions). 256 blocks x 512 threads.
// ---------------------------------------------------------------------------

// LSTM step via MFMA, split-bf16 3-term. Block owns 16 gate-interleaved rows
// (= 4 complete units), K split 8-way across waves, fused gate tail.
template<int K, int XE>
__device__ __forceinline__ void lstm_phase(
    const unsigned short* __restrict__ Xe_h, const unsigned short* __restrict__ Xe_l,
    const unsigned short* __restrict__ Xr_h, const unsigned short* __restrict__ Xr_l,
    const unsigned short* __restrict__ Wh,  const unsigned short* __restrict__ Wl,
    const float* __restrict__ bih, const float* __restrict__ bhh,
    float* __restrict__ c_io,
    unsigned short* d1h, unsigned short* d1l, int d1s, int d1o,
    unsigned short* d2h, unsigned short* d2l, int d2s, int d2o,
    float* hf32,
    float (*Gs)[32][16], float (*Gr)[16])
{
    const int tid = threadIdx.x;
    const int wave = tid >> 6, lane = tid & 63;
    const int quad = lane >> 4, l15 = lane & 15;
    const int n0 = blockIdx.x * 16;
    constexpr int Kq = K >> 3;           // per-wave K span (8 waves)
    const int kb = wave * Kq;
    const int col = quad * 8;
    f32x4 acc0 = {0.f,0.f,0.f,0.f}, acc1 = {0.f,0.f,0.f,0.f};
    const unsigned short* wrh = Wh + (size_t)(n0 + l15) * K + kb + col;
    const unsigned short* wrl = Wl + (size_t)(n0 + l15) * K + kb + col;
    #pragma unroll 4
    for (int ks = 0; ks < Kq; ks += 32) {
        const int k = kb + ks;
        const unsigned short *ah, *al; int as_;
        if (XE != 0 && k < XE) { ah = Xe_h + k + col; al = Xe_l + k + col; as_ = EMB_; }
        else                   { ah = Xr_h + (k - XE) + col; al = Xr_l + (k - XE) + col; as_ = 2048; }
        bf16x8 a0h = *(const bf16x8*)(ah + l15 * as_);
        bf16x8 a0l = *(const bf16x8*)(al + l15 * as_);
        bf16x8 a1h = *(const bf16x8*)(ah + (16 + l15) * as_);
        bf16x8 a1l = *(const bf16x8*)(al + (16 + l15) * as_);
        bf16x8 bh  = *(const bf16x8*)(wrh + ks);
        bf16x8 bl  = *(const bf16x8*)(wrl + ks);
        acc0 = __builtin_amdgcn_mfma_f32_16x16x32_bf16(a0h, bh, acc0, 0, 0, 0);
        acc1 = __builtin_amdgcn_mfma_f32_16x16x32_bf16(a1h, bh, acc1, 0, 0, 0);
        acc0 = __builtin_amdgcn_mfma_f32_16x16x32_bf16(a0h, bl, acc0, 0, 0, 0);
        acc1 = __builtin_amdgcn_mfma_f32_16x16x32_bf16(a1h, bl, acc1, 0, 0, 0);
        acc0 = __builtin_amdgcn_mfma_f32_16x16x32_bf16(a0l, bh, acc0, 0, 0, 0);
        acc1 = __builtin_amdgcn_mfma_f32_16x16x32_bf16(a1l, bh, acc1, 0, 0, 0);
    }
    // C/D layout: col = lane&15 (gate row), row = quad*4 + reg (batch) [m89]
    #pragma unroll
    for (int rr = 0; rr < 4; rr++) {
        Gs[wave][quad * 4 + rr][l15]      = acc0[rr];
        Gs[wave][16 + quad * 4 + rr][l15] = acc1[rr];
    }
    __syncthreads();
    {
        const int b = tid >> 4, nl = tid & 15;   // 512 outputs, 1 pass
        float g = 0.f;
        #pragma unroll
        for (int w = 0; w < 8; w++) g += Gs[w][b][nl];
        const int jn = n0 + nl;
        const int j = (jn & 3) * H_ + (jn >> 2); // original (un-interleaved) row
        Gr[b][nl] = g + bih[j] + bhh[j];
    }
    __syncthreads();
    if (tid < 128) {
        const int b = tid & 31, ul = tid >> 5;
        const int u = (n0 >> 2) + ul;
        const float gi = Gr[b][ul * 4 + 0];
        const float gf = Gr[b][ul * 4 + 1];
        const float gg = Gr[b][ul * 4 + 2];
        const float go = Gr[b][ul * 4 + 3];
        const float cold = c_io[b * H_ + u];
        const float si = 1.f / (1.f + __expf(-gi));
        const float sf = 1.f / (1.f + __expf(-gf));
        const float so = 1.f / (1.f + __expf(-go));
        const float cn = sf * cold + si * tanhf(gg);
        const float hn = so * tanhf(cn);
        c_io[b * H_ + u] = cn;
        unsigned short hh, hl;
        f2hilo(hn, hh, hl);
        d1h[b * d1s + d1o + u] = hh;
        d1l[b * d1s + d1o + u] = hl;
        d2h[b * d2s + d2o + u] = hh;
        d2l[b * d2s + d2o + u] = hl;
        if (hf32) hf32[b * H_ + u] = hn;
    }
}

// Small GEMM out[32,1024] = X[32,K] @ W[1024,K]^T + bias, K split 8-way.
// MODE 0: fp32 out (keybuf) + atomic partial of score(s=t) = keyv . htop.
// MODE 1: bf16 out (combbf) + hi/lo feed slot.
template<int K, int MODE>
__device__ __forceinline__ void gemm32_phase(
    const unsigned short* __restrict__ Xh, const unsigned short* __restrict__ Xl,
    const unsigned short* __restrict__ Wh, const unsigned short* __restrict__ Wl,
    const float* __restrict__ bias,
    float* outf, unsigned short* outbf,
    unsigned short* dh, unsigned short* dl,
    const float* htop, float* score_row,
    float (*Gs)[32][16])
{
    const int tid = threadIdx.x;
    const int wave = tid >> 6, lane = tid & 63;
    const int quad = lane >> 4, l15 = lane & 15;
    const int n0 = blockIdx.x * 16;
    constexpr int Kq = K >> 3;
    const int kb = wave * Kq;
    const int col = quad * 8;
    f32x4 acc0 = {0.f,0.f,0.f,0.f}, acc1 = {0.f,0.f,0.f,0.f};
    const unsigned short* x0h = Xh + (size_t)l15 * K + kb + col;
    const unsigned short* x0l = Xl + (size_t)l15 * K + kb + col;
    const unsigned short* x1h = Xh + (size_t)(16 + l15) * K + kb + col;
    const unsigned short* x1l = Xl + (size_t)(16 + l15) * K + kb + col;
    const unsigned short* wrh = Wh + (size_t)(n0 + l15) * K + kb + col;
    const unsigned short* wrl = Wl + (size_t)(n0 + l15) * K + kb + col;
    #pragma unroll 4
    for (int ks = 0; ks < Kq; ks += 32) {
        bf16x8 a0h = *(const bf16x8*)(x0h + ks);
        bf16x8 a0l = *(const bf16x8*)(x0l + ks);
        bf16x8 a1h = *(const bf16x8*)(x1h + ks);
        bf16x8 a1l = *(const bf16x8*)(x1l + ks);
        bf16x8 bh  = *(const bf16x8*)(wrh + ks);
        bf16x8 bl  = *(const bf16x8*)(wrl + ks);
        acc0 = __builtin_amdgcn_mfma_f32_16x16x32_bf16(a0h, bh, acc0, 0, 0, 0);
        acc1 = __builtin_amdgcn_mfma_f32_16x16x32_bf16(a1h, bh, acc1, 0, 0, 0);
        acc0 = __builtin_amdgcn_mfma_f32_16x16x32_bf16(a0h, bl, acc0, 0, 0, 0);
        acc1 = __builtin_amdgcn_mfma_f32_16x16x32_bf16(a1h, bl, acc1, 0, 0, 0);
        acc0 = __builtin_amdgcn_mfma_f32_16x16x32_bf16(a0l, bh, acc0, 0, 0, 0);
        acc1 = __builtin_amdgcn_mfma_f32_16x16x32_bf16(a1l, bh, acc1, 0, 0, 0);
    }
    #pragma unroll
    for (int rr = 0; rr < 4; rr++) {
        Gs[wave][quad * 4 + rr][l15]      = acc0[rr];
        Gs[wave][16 + quad * 4 + rr][l15] = acc1[rr];
    }
    __syncthreads();
    {
        const int b = tid >> 4, nl = tid & 15;
        const int n = n0 + nl;
        float v = bias[n];
        #pragma unroll
        for (int w = 0; w < 8; w++) v += Gs[w][b][nl];
        if (MODE == 0) {
            outf[b * H_ + n] = v;
            float pv = v * htop[b * H_ + n];
            #pragma unroll
            for (int off = 8; off > 0; off >>= 1) pv += __shfl_down(pv, off, 16);
            if ((tid & 15) == 0) atomicAdd(score_row + b, pv);
        } else {
            outbf[b * H_ + n] = f2bf(v);
            unsigned short hh, hl;
            f2hilo(v, hh, hl);
            dh[b * 2048 + n] = hh;
            dl[b * 2048 + n] = hl;
        }
    }
}

// Historical scores s < t: one (s,b) dot per wave-iteration across blocks 64..255.
__device__ __forceinline__ void scores_phase(
    int t, const float* __restrict__ hbuf, const float* __restrict__ keybuf,
    float* __restrict__ score_g)
{
    const int gw = (blockIdx.x - 64) * 8 + (threadIdx.x >> 6);
    const int lane = threadIdx.x & 63;
    const float* ht_t = hbuf + (size_t)t * B_ * H_;
    for (int p = gw; p < t * 32; p += 192 * 8) {
        const int s = p >> 5, b = p & 31;
        const float* kv = keybuf + ((size_t)s * B_ + b) * H_;
        const float* ht = ht_t + (size_t)b * H_;
        float acc = 0.f;
        #pragma unroll
        for (int j = 0; j < 16; j++) acc += kv[lane + 64 * j] * ht[lane + 64 * j];
        #pragma unroll
        for (int off = 32; off > 0; off >>= 1) acc += __shfl_down(acc, off, 64);
        if (lane == 0) score_g[s * 32 + b] = acc;
    }
}

// Softmax + summary. 8 blocks per batch row (slice of 128 H-cols each);
// softmax recomputed redundantly per block (64 values, cheap & deterministic).
__device__ __forceinline__ void attn_phase(
    int t, const int* __restrict__ tok, const float* __restrict__ hbuf,
    const float* __restrict__ score_g, float* __restrict__ dist,
    unsigned short* __restrict__ cath, unsigned short* __restrict__ catl,
    float* dsh, float (*smp)[128])
{
    const int b = blockIdx.x >> 3, slice = blockIdx.x & 7;
    const int tid = threadIdx.x;
    if (tid < 64) {
        float v = (tid <= t) ? score_g[tid * 32 + b] +
                  ((tok[tid * 32 + b] == 0) ? -99999.0f : 0.0f) : -1e30f;
        float m = v;
        #pragma unroll
        for (int off = 32; off > 0; off >>= 1) m = fmaxf(m, __shfl_down(m, off, 64));
        m = __shfl(m, 0, 64);
        float e = (tid <= t) ? __expf(v - m) : 0.f;
        float ss = e;
        #pragma unroll
        for (int off = 32; off > 0; off >>= 1) ss += __shfl_down(ss, off, 64);
        ss = __shfl(ss, 0, 64);
        dsh[tid] = e / ss;
    }
    __syncthreads();
    const int c = tid & 127, q = tid >> 7;
    const int col = slice * 128 + c;
    float sm = 0.f;
    for (int s = q; s <= t; s += 4)
        sm += dsh[s] * hbuf[((size_t)s * B_ + b) * H_ + col];
    smp[q][c] = sm;
    __syncthreads();
    if (tid < 128) {
        const int c2 = slice * 128 + tid;
        float total = smp[0][tid] + smp[1][tid] + smp[2][tid] + smp[3][tid];
        unsigned short hh, hl;
        f2hilo(total, hh, hl);
        cath[b * 2048 + 1024 + c2] = hh;
        catl[b * 2048 + 1024 + c2] = hl;
        const float htv = hbuf[((size_t)t * B_ + b) * H_ + c2];
        f2hilo(htv, hh, hl);
        cath[b * 2048 + c2] = hh;
        catl[b * 2048 + c2] = hl;
    }
    if (slice == 0 && tid <= t)
        dist[((size_t)t * T_ + tid) * B_ + b] = dsh[tid];
}

// ---------------------------------------------------------------------------
// Persistent cooperative kernel: the whole 64-step recurrence, 5 custom grid
// barriers per step (fast two-level monotonic barrier, not cg::sync).
// ---------------------------------------------------------------------------
struct DecParams {
    const int* tok;
    const unsigned short *Xeh, *Xel;
    unsigned short *xr0h, *xr0l, *xr1h, *xr1l;
    const unsigned short *W0h, *W0l, *W1h, *W1l, *Wkh, *Wkl, *Wch, *Wcl;
    const float *bih0, *bhh0, *bih1, *bhh1, *bk, *bc;
    float *c0b, *c1b;
    float *hbuf, *keybuf, *score_g, *dist;
    unsigned short *hbh, *hbl, *cath, *catl, *combbf;
    unsigned int *bgrp, *broot, *bgen;
};

__global__ __launch_bounds__(512) void decode_loop_kernel(DecParams p)
{
    __shared__ __align__(16) float Gs[8][32][16];
    __shared__ float Gr[32][16];
    __shared__ float dsh[64];
    __shared__ float smp[4][128];
    const int blk = blockIdx.x;
    const int tid = threadIdx.x;
    unsigned int ep = 0;
    for (int t = 0; t < T_; t++) {
        const size_t cur = (size_t)(t & 1) * B_ * 2048;
        const size_t nxt = (size_t)((t + 1) & 1) * B_ * 2048;
        const size_t to1 = (size_t)t * B_ * H_;
        // zero the s=t score row (consumed by P3 atomics, 2 barriers later)
        if (blk == 0 && tid < 32) p.score_g[t * 32 + tid] = 0.f;
        // P1: layer 0.  X = [Xe(t) | feed | h0prev]
        lstm_phase<2560, 512>(
            p.Xeh + (size_t)t * B_ * EMB_, p.Xel + (size_t)t * B_ * EMB_,
            p.xr0h + cur, p.xr0l + cur, p.W0h, p.W0l, p.bih0, p.bhh0, p.c0b,
            p.xr0h + nxt, p.xr0l + nxt, 2048, 1024,
            p.xr1h + cur, p.xr1l + cur, 2048, 0,
            nullptr, Gs, Gr);
        gbar_sync(p.bgrp, p.broot, p.bgen, ++ep);
        // P2: layer 1.  X = [h0cur | h1prev]
        lstm_phase<2048, 0>(
            p.xr1h + cur, p.xr1l + cur, p.xr1h + cur, p.xr1l + cur,
            p.W1h, p.W1l, p.bih1, p.bhh1, p.c1b,
            p.xr1h + nxt, p.xr1l + nxt, 2048, 1024,
            p.hbh + to1, p.hbl + to1, 1024, 0,
            p.hbuf + to1, Gs, Gr);
        gbar_sync(p.bgrp, p.broot, p.bgen, ++ep);
        // P3: keyv(t) + score(t) partials (blocks 0..63) || scores s<t (64..255)
        if (blk < 64)
            gemm32_phase<1024, 0>(p.hbh + to1, p.hbl + to1, p.Wkh, p.Wkl, p.bk,
                p.keybuf + to1, nullptr, nullptr, nullptr,
                p.hbuf + to1, p.score_g + t * 32, Gs);
        else
            scores_phase(t, p.hbuf, p.keybuf, p.score_g);
        gbar_sync(p.bgrp, p.broot, p.bgen, ++ep);
        // P4: softmax + summary + cat + dist
        attn_phase(t, p.tok, p.hbuf, p.score_g, p.dist, p.cath, p.catl, dsh, smp);
        gbar_sync(p.bgrp, p.broot, p.bgen, ++ep);
        // P5: comb = cat @ Wc^T + bc -> combbf + next feed slot (blocks 0..63)
        if (blk < 64)
            gemm32_phase<2048, 1>(p.cath, p.catl, p.Wch, p.Wcl, p.bc,
                nullptr, p.combbf + to1, p.xr0h + nxt, p.xr0l + nxt,
                nullptr, nullptr, Gs);
        gbar_sync(p.bgrp, p.broot, p.bgen, ++ep);
    }
}

// ---------------------------------------------------------------------------
// fp32 -> bf16 cast (n4 float4 groups) — used for Wp only.
// ---------------------------------------------------------------------------
__global__ __launch_bounds__(256) void cast_bf16_kernel(
    const float* __restrict__ src, unsigned short* __restrict__ dst, int n4)
{
    int idx = blockIdx.x * 256 + threadIdx.x;
    int stride = gridDim.x * 256;
    for (int i = idx; i < n4; i += stride) {
        float4 v = ((const float4*)src)[i];
        ushort4 o;
        o.x = f2bf(v.x); o.y = f2bf(v.y); o.z = f2bf(v.z); o.w = f2bf(v.w);
        ((ushort4*)dst)[i] = o;
    }
}

// ---------------------------------------------------------------------------
// Logits GEMM: (2048 x 1024) @ Wp^T (32000 x 1024) + bp, bf16 MFMA 16x16x32.
// ---------------------------------------------------------------------------
__global__ __launch_bounds__(256) void logits_mfma_kernel(
    const __bf16* __restrict__ Abf, const __bf16* __restrict__ Bbf,
    const float* __restrict__ bp, float* __restrict__ out)
{
    __shared__ __align__(16) __bf16 As[128 * 32];
    __shared__ __align__(16) __bf16 Bs[128 * 32];
    const int tid = threadIdx.x;
    const int lane = tid & 63;
    const int wave = tid >> 6;
    const int quad = lane >> 4, l15 = lane & 15;
    const int m0 = blockIdx.y * 128, n0 = blockIdx.x * 128;
    const int wm = wave >> 1, wn = wave & 1;
    const f32x4 vzero = {0.f, 0.f, 0.f, 0.f};
    f32x4 acc[4][4];
    #pragma unroll
    for (int mt = 0; mt < 4; mt++)
        #pragma unroll
        for (int nt = 0; nt < 4; nt++) acc[mt][nt] = vzero;

    for (int k0 = 0; k0 < 1024; k0 += 32) {
        #pragma unroll
        for (int i = 0; i < 2; i++) {
            int idx = i * 256 + tid;
            int row = idx >> 2, co = (idx & 3) * 8;
            ((uint4*)As)[idx] = *(const uint4*)(Abf + (size_t)(m0 + row) * 1024 + k0 + co);
            ((uint4*)Bs)[idx] = *(const uint4*)(Bbf + (size_t)(n0 + row) * 1024 + k0 + co);
        }
        __syncthreads();
        bf16x8 af[4], bfr[4];
        #pragma unroll
        for (int mt = 0; mt < 4; mt++)
            af[mt] = *(const bf16x8*)&As[(wm * 64 + mt * 16 + l15) * 32 + quad * 8];
        #pragma unroll
        for (int nt = 0; nt < 4; nt++)
            bfr[nt] = *(const bf16x8*)&Bs[(wn * 64 + nt * 16 + l15) * 32 + quad * 8];
        #pragma unroll
        for (int mt = 0; mt < 4; mt++)
            #pragma unroll
            for (int nt = 0; nt < 4; nt++)
                acc[mt][nt] = __builtin_amdgcn_mfma_f32_16x16x32_bf16(
                    af[mt], bfr[nt], acc[mt][nt], 0, 0, 0);
        __syncthreads();
    }
    #pragma unroll
    for (int mt = 0; mt < 4; mt++) {
        #pragma unroll
        for (int nt = 0; nt < 4; nt++) {
            int gcol = n0 + wn * 64 + nt * 16 + l15;
            int growb = m0 + wm * 64 + mt * 16 + quad * 4;
            float bpv = bp[gcol];
            #pragma unroll
            for (int rr = 0; rr < 4; rr++)
                out[(size_t)(growb + rr) * V_ + gcol] = acc[mt][nt][rr] + bpv;
        }
    }
}

// ---------------------------------------------------------------------------
// Per-row max / sumexp / copy-weight from fp32 logits. Grid: T*B blocks.
// ---------------------------------------------------------------------------
__global__ __launch_bounds__(256) void rowstats_kernel(
    const float* __restrict__ logits, float* __restrict__ stats)
{
    const int row = blockIdx.x; const int tid = threadIdx.x;
    const float4* p4 = (const float4*)(logits + (size_t)row * V_);
    __shared__ float red[8];
    const int lane = tid & 63, wave = tid >> 6;
    float m = -1e30f;
    for (int i = tid; i < V_ / 4; i += 256) {
        float4 u = p4[i];
        m = fmaxf(m, fmaxf(fmaxf(u.x, u.y), fmaxf(u.z, u.w)));
    }
    #pragma unroll
    for (int off = 32; off > 0; off >>= 1) m = fmaxf(m, __shfl_down(m, off, 64));
    if (lane == 0) red[wave] = m;
    __syncthreads();
    if (tid == 0) {
        float mm = red[0];
        for (int w = 1; w < 4; w++) mm = fmaxf(mm, red[w]);
        red[4] = mm;
    }
    __syncthreads();
    const float M = red[4];
    float s = 0.f;
    for (int i = tid; i < V_ / 4; i += 256) {
        float4 u = p4[i];
        s += __expf(u.x - M) + __expf(u.y - M) + __expf(u.z - M) + __expf(u.w - M);
    }
    #pragma unroll
    for (int off = 32; off > 0; off >>= 1) s += __shfl_down(s, off, 64);
    if (lane == 0) red[wave] = s;
    __syncthreads();
    if (tid == 0) {
        float S = red[0] + red[1] + red[2] + red[3];
        float lc = logits[(size_t)row * V_ + COPY_ID_];
        float cw = __expf(lc - M) / S;
        stats[row * 4 + 0] = M;
        stats[row * 4 + 1] = S;
        stats[row * 4 + 2] = cw;
    }
}

__global__ __launch_bounds__(64) void fixup_compute_kernel(
    const float* __restrict__ logits, const float* __restrict__ stats,
    const int* __restrict__ tokens, const float* __restrict__ dist_all,
    float* __restrict__ fixval)
{
    const int bid = blockIdx.x;          // t*B + b
    const int t = bid >> 5, b = bid & 31;
    const int s = threadIdx.x;
    if (s > t) return;
    const int v = tokens[s * B_ + b];
    float d = 0.f;
    for (int s2 = 0; s2 <= t; s2++)
        if (tokens[s2 * B_ + b] == v)
            d += dist_all[((size_t)t * T_ + s2) * B_ + b];
    const float M = stats[bid * 4], S = stats[bid * 4 + 1], cw = stats[bid * 4 + 2];
    const float l = logits[(size_t)bid * V_ + v];
    const float p = __expf(l - M) / S;
    fixval[((size_t)t * T_ + s) * B_ + b] = __logf(cw * (EPS_ + d) + (1.f - cw) * p);
}

__global__ __launch_bounds__(256) void finalize_kernel(
    float* __restrict__ logits, const float* __restrict__ stats)
{
    const int row = blockIdx.x; const int tid = threadIdx.x;
    float4* p4 = (float4*)(logits + (size_t)row * V_);
    const float M = stats[row * 4], S = stats[row * 4 + 1], cw = stats[row * 4 + 2];
    const float inv = 1.f / S, omc = 1.f - cw, ce = cw * EPS_;
    for (int i = tid; i < V_ / 4; i += 256) {
        float4 u = p4[i];
        u.x = __logf(omc * (__expf(u.x - M) * inv) + ce);
        u.y = __logf(omc * (__expf(u.y - M) * inv) + ce);
        u.z = __logf(omc * (__expf(u.z - M) * inv) + ce);
        u.w = __logf(omc * (__expf(u.w - M) * inv) + ce);
        p4[i] = u;
    }
}

__global__ __launch_bounds__(64) void fixup_apply_kernel(
    float* __restrict__ logits, const int* __restrict__ tokens,
    const float* __restrict__ fixval)
{
    const int bid = blockIdx.x; const int t = bid >> 5, b = bid & 31;
    const int s = threadIdx.x;
    if (s > t) return;
    const int v = tokens[s * B_ + b];
    logits[(size_t)bid * V_ + v] = fixval[((size_t)t * T_ + s) * B_ + b];
}

// ---------------------------------------------------------------------------
extern "C" void kernel_launch(void* const* d_in, const int* in_sizes, int n_in,
                              void* d_out, int out_size, void* d_ws, size_t ws_size,
                              hipStream_t stream)
{
    const int*   tok  = (const int*)d_in[0];
    const float* h0i  = (const float*)d_in[1];
    const float* c0i  = (const float*)d_in[2];
    const float* E    = (const float*)d_in[3];
    const float* Wih0 = (const float*)d_in[4];
    const float* Whh0 = (const float*)d_in[5];
    const float* bih0 = (const float*)d_in[6];
    const float* bhh0 = (const float*)d_in[7];
    const float* Wih1 = (const float*)d_in[8];
    const float* Whh1 = (const float*)d_in[9];
    const float* bih1 = (const float*)d_in[10];
    const float* bhh1 = (const float*)d_in[11];
    const float* Wk   = (const float*)d_in[12];
    const float* bk   = (const float*)d_in[13];
    const float* Wc   = (const float*)d_in[14];
    const float* bc   = (const float*)d_in[15];
    const float* Wp   = (const float*)d_in[16];
    const float* bp   = (const float*)d_in[17];
    float* out = (float*)d_out;

    // ---- workspace (fp32 side) ----
    float* ws = (float*)d_ws;
    size_t off = 0;
    float* hbuf   = ws + off; off += (size_t)T_ * B_ * H_;     // fp32 htop, attn input
    float* keybuf = ws + off; off += (size_t)T_ * B_ * H_;
    float* dist   = ws + off; off += (size_t)T_ * T_ * B_;
    float* fixv   = ws + off; off += (size_t)T_ * T_ * B_;
    float* c0b    = ws + off; off += B_ * H_;
    float* c1b    = ws + off; off += B_ * H_;
    float* stats  = ws + off; off += (size_t)T_ * B_ * 4;
    float* score_g= ws + off; off += (size_t)T_ * B_;
    unsigned int* barmem = (unsigned int*)(ws + off); off += 1024; // grid barrier state (4KB)
    unsigned short* combbf = (unsigned short*)(ws + off); off += (size_t)T_ * B_ * H_ / 2;
    unsigned short* Wpbf   = (unsigned short*)(ws + off); off += (size_t)V_ * H_ / 2;

    // ---- scratch carved from d_out (262 MB; only the epilogue writes logits,
    //      all of this is dead by then). ~102 MB total. ----
    unsigned short* os = (unsigned short*)d_out;
    size_t so = 0;
    unsigned short* W0h = os + so; so += (size_t)4096 * 2560;
    unsigned short* W0l = os + so; so += (size_t)4096 * 2560;
    unsigned short* W1h = os + so; so += (size_t)4096 * 2048;
    unsigned short* W1l = os + so; so += (size_t)4096 * 2048;
    unsigned short* Wkh = os + so; so += (size_t)1024 * 1024;
    unsigned short* Wkl = os + so; so += (size_t)1024 * 1024;
    unsigned short* Wch = os + so; so += (size_t)1024 * 2048;
    unsigned short* Wcl = os + so; so += (size_t)1024 * 2048;
    unsigned short* Xeh = os + so; so += (size_t)T_ * B_ * EMB_;
    unsigned short* Xel = os + so; so += (size_t)T_ * B_ * EMB_;
    unsigned short* xr0h = os + so; so += (size_t)2 * B_ * 2048;  // [2][32][feed|h0prev]
    unsigned short* xr0l = os + so; so += (size_t)2 * B_ * 2048;
    unsigned short* xr1h = os + so; so += (size_t)2 * B_ * 2048;  // [2][32][h0cur|h1prev]
    unsigned short* xr1l = os + so; so += (size_t)2 * B_ * 2048;
    unsigned short* hbh  = os + so; so += (size_t)T_ * B_ * H_;   // htop hi (keyv input)
    unsigned short* hbl  = os + so; so += (size_t)T_ * B_ * H_;
    unsigned short* cath = os + so; so += (size_t)B_ * 2048;
    unsigned short* catl = os + so; so += (size_t)B_ * 2048;

    // ---- one-time prep ----
    hipMemsetAsync(barmem, 0, 1024 * sizeof(unsigned int), stream);
    hipMemcpyAsync(c0b, c0i,           B_ * H_ * 4, hipMemcpyDeviceToDevice, stream);
    hipMemcpyAsync(c1b, c0i + B_ * H_, B_ * H_ * 4, hipMemcpyDeviceToDevice, stream);
    pack_gates_kernel<<<10240, 256, 0, stream>>>(Wih0, 1536, Whh0, 2560, W0h, W0l);
    pack_gates_kernel<<<8192,  256, 0, stream>>>(Wih1, 1024, Whh1, 2048, W1h, W1l);
    pack_plain_kernel<<<1024,  256, 0, stream>>>(Wk, Wkh, Wkl, 1024 * 1024 / 4);
    pack_plain_kernel<<<2048,  256, 0, stream>>>(Wc, Wch, Wcl, 1024 * 2048 / 4);
    embed_hilo_kernel<<<1024,  256, 0, stream>>>(E, tok, Xeh, Xel);
    init_states_kernel<<<128,  256, 0, stream>>>(h0i, xr0h, xr0l, xr1h, xr1l);
    cast_bf16_kernel<<<2048,   256, 0, stream>>>(Wp, Wpbf, V_ * H_ / 4);

    // ---- recurrent loop: one persistent cooperative kernel ----
    DecParams P;
    P.tok = tok; P.Xeh = Xeh; P.Xel = Xel;
    P.xr0h = xr0h; P.xr0l = xr0l; P.xr1h = xr1h; P.xr1l = xr1l;
    P.W0h = W0h; P.W0l = W0l; P.W1h = W1h; P.W1l = W1l;
    P.Wkh = Wkh; P.Wkl = Wkl; P.Wch = Wch; P.Wcl = Wcl;
    P.bih0 = bih0; P.bhh0 = bhh0; P.bih1 = bih1; P.bhh1 = bhh1;
    P.bk = bk; P.bc = bc;
    P.c0b = c0b; P.c1b = c1b;
    P.hbuf = hbuf; P.keybuf = keybuf; P.score_g = score_g; P.dist = dist;
    P.hbh = hbh; P.hbl = hbl; P.cath = cath; P.catl = catl; P.combbf = combbf;
    P.bgrp = barmem;            // 16 groups x 32-uint stride (128B lines)
    P.broot = barmem + 512;
    P.bgen = barmem + 544;      // separate 128B line from root
    void* kargs[] = { (void*)&P };
    hipLaunchCooperativeKernel(reinterpret_cast<void*>(decode_loop_kernel),
                               dim3(256), dim3(512), kargs, 0, stream);

    // ---- epilogue (overwrites the d_out scratch with real logits) ----
    dim3 g1(V_ / 128, (T_ * B_) / 128);
    logits_mfma_kernel<<<g1, 256, 0, stream>>>(
        (const __bf16*)combbf, (const __bf16*)Wpbf, bp, out);
    rowstats_kernel<<<T_ * B_, 256, 0, stream>>>(out, stats);
    fixup_compute_kernel<<<T_ * B_, T_, 0, stream>>>(out, stats, tok, dist, fixv);
    finalize_kernel<<<T_ * B_, 256, 0, stream>>>(out, stats);
    fixup_apply_kernel<<<T_ * B_, T_, 0, stream>>>(out, tok, fixv);
}